// Round 23
// baseline (195.693 us; speedup 1.0000x reference)
//
#include <hip/hip_runtime.h>
#include <hip/hip_bf16.h>
#include <math.h>

#define TT 32
#define NN 2048
#define FF 64

typedef float f32x4 __attribute__((ext_vector_type(4)));
typedef __bf16 bf16x8 __attribute__((ext_vector_type(8)));
typedef unsigned short u16x8 __attribute__((ext_vector_type(8)));

__device__ __forceinline__ unsigned short f2bf(float f) {
    __bf16 h = (__bf16)f;
    return __builtin_bit_cast(unsigned short, h);
}

// ---------------------------------------------------------------------------
// K_S: wide scoring kernel. grid (8, 32) x 256.  (R22-proven verbatim)
// ---------------------------------------------------------------------------
__global__ __launch_bounds__(256) void score_kernel(
    const float* __restrict__ X, const float* __restrict__ mask,
    const float* __restrict__ scorer,
    double* __restrict__ scores, unsigned short* __restrict__ Xbf)
{
    const int t = blockIdx.y, tid = threadIdx.x;
    const int n = blockIdx.x * 256 + tid;
    __shared__ float scf[64];
    if (tid < 64) scf[tid] = scorer[tid];
    __syncthreads();

    double nrm = 0.0;
#pragma unroll
    for (int f = 0; f < 64; ++f) nrm += (double)scf[f] * (double)scf[f];
    const double inv = 1.0 / sqrt(nrm);

    const float* xr = X + ((size_t)t * NN + n) * FF;
    unsigned short* xo = Xbf + ((size_t)t * NN + n) * FF;
    double s = 0.0;
#pragma unroll
    for (int f = 0; f < 64; f += 4) {
        float4 v = *(const float4*)(xr + f);
        s += (double)v.x * (double)scf[f]   + (double)v.y * (double)scf[f+1]
           + (double)v.z * (double)scf[f+2] + (double)v.w * (double)scf[f+3];
        ushort4 pk = make_ushort4(f2bf(v.x), f2bf(v.y), f2bf(v.z), f2bf(v.w));
        *(ushort4*)(xo + f) = pk;
    }
    scores[t * NN + n] = s * inv + (double)mask[t * NN + n];
}

// ---------------------------------------------------------------------------
// K_A select v4 (R22-proven verbatim): per-wave 128-elem reg bitonic ->
// merge-and-truncate tree -> (idx, tanh(val)).
// ---------------------------------------------------------------------------
__global__ __launch_bounds__(1024) void select_kernel(
    const double* __restrict__ scores,
    int* __restrict__ tkidx, float* __restrict__ tkval)
{
    const int t = blockIdx.x, tid = threadIdx.x;
    const int lane = tid & 63, w = tid >> 6;
    __shared__ double sk[1024];
    __shared__ int    si[1024];

    double v0 = scores[t * NN + (w << 7) + lane];
    double v1 = scores[t * NN + (w << 7) + 64 + lane];
    int    i0 = (w << 7) + lane;
    int    i1 = (w << 7) + 64 + lane;

#define BETTER(av, ai, bv, bi) ((av) > (bv) || ((av) == (bv) && (ai) < (bi)))
#pragma unroll
    for (int k = 2; k <= 128; k <<= 1) {
#pragma unroll
        for (int j = 64; j > 0; j >>= 1) {
            if (j > (k >> 1)) continue;
            if (j == 64) {
                const bool ib = BETTER(v0, i0, v1, i1);
                if (!ib) {
                    const double tv = v0; v0 = v1; v1 = tv;
                    const int ti = i0; i0 = i1; i1 = ti;
                }
            } else {
                {
                    const double pv = __shfl_xor(v0, j);
                    const int    pi = __shfl_xor(i0, j);
                    const bool lower = (lane & j) == 0;
                    const bool up = ((lane & k) == 0);
                    const bool ib = BETTER(v0, i0, pv, pi);
                    const bool keep = (up == lower) ? ib : !ib;
                    if (!keep) { v0 = pv; i0 = pi; }
                }
                {
                    const double pv = __shfl_xor(v1, j);
                    const int    pi = __shfl_xor(i1, j);
                    const bool lower = (lane & j) == 0;
                    const bool up = (k == 64) ? false : ((lane & k) == 0);
                    const bool ib = BETTER(v1, i1, pv, pi);
                    const bool keep = (up == lower) ? ib : !ib;
                    if (!keep) { v1 = pv; i1 = pi; }
                }
            }
        }
    }
    sk[(w << 6) + lane] = v0;
    si[(w << 6) + lane] = i0;
    __syncthreads();

#pragma unroll
    for (int round = 0; round < 4; ++round) {
        const int nl = 8 >> round;
        double cv = 0.0; int ci = 0;
        const bool active = (w < nl);
        if (active) {
            const int la = (w << 1), lb = (w << 1) + 1;
            const double av = sk[(la << 6) + lane];
            const int    ai = si[(la << 6) + lane];
            const double bv = sk[(lb << 6) + 63 - lane];
            const int    bi = si[(lb << 6) + 63 - lane];
            if (BETTER(av, ai, bv, bi)) { cv = av; ci = ai; }
            else                        { cv = bv; ci = bi; }
#pragma unroll
            for (int j = 32; j > 0; j >>= 1) {
                const double pv = __shfl_xor(cv, j);
                const int    pi = __shfl_xor(ci, j);
                const bool lower = (lane & j) == 0;
                const bool ib = BETTER(cv, ci, pv, pi);
                const bool keep = lower ? ib : !ib;
                if (!keep) { cv = pv; ci = pi; }
            }
        }
        __syncthreads();
        if (active) {
            sk[(w << 6) + lane] = cv;
            si[(w << 6) + lane] = ci;
        }
        __syncthreads();
    }
#undef BETTER

    if (tid < 64) {
        tkidx[t * 64 + tid] = si[tid];
        tkval[t * 64 + tid] = tanhf((float)sk[tid]);
    }
}

// ---------------------------------------------------------------------------
// K_B qchain v6 (R20/R22-proven verbatim): 64 blocks x 256, 2 barriers/step.
// ---------------------------------------------------------------------------
__global__ __launch_bounds__(256) void qchain_kernel(
    const float* __restrict__ Q0,
    const float* __restrict__ Uu, const float* __restrict__ Ur,
    const float* __restrict__ Uh,
    const float* __restrict__ Wu, const float* __restrict__ Wr,
    const float* __restrict__ Wh,
    const float* __restrict__ bu, const float* __restrict__ br,
    const float* __restrict__ bh,
    const int* __restrict__ tkidx, const float* __restrict__ tkval,
    const float* __restrict__ X, unsigned short* __restrict__ Qtr)
{
    const int j = blockIdx.x, tid = threadIdx.x;
    const int w = tid >> 6, l = tid & 63;
    const int i = (w << 4) + (l & 15);
    const int fq = l >> 4, fb = fq << 4;

    __shared__ __align__(16) float zsh[TT][64];
    __shared__ __align__(16) float wzl[3 * TT * 64];
    __shared__ __align__(16) float qd[2][64];
    __shared__ __align__(16) float rr[64];

    {
        const int tt = tid >> 3, p8 = (tid & 7) << 3;
        const int idxt = tkidx[tt * 64 + j];
        const float th = tkval[tt * 64 + j];
        const float* xr = X + ((size_t)tt * NN + idxt) * FF + p8;
        float4 v0 = *(const float4*)(xr);
        float4 v1 = *(const float4*)(xr + 4);
        zsh[tt][p8]     = v0.x * th; zsh[tt][p8 + 1] = v0.y * th;
        zsh[tt][p8 + 2] = v0.z * th; zsh[tt][p8 + 3] = v0.w * th;
        zsh[tt][p8 + 4] = v1.x * th; zsh[tt][p8 + 5] = v1.y * th;
        zsh[tt][p8 + 6] = v1.z * th; zsh[tt][p8 + 7] = v1.w * th;
    }

    float uu[16], ur[16], uh[16], wu[16], wr[16], wh[16];
#pragma unroll
    for (int e = 0; e < 16; e += 4) {
        float4 a = *(const float4*)(Uu + i * 64 + fb + e);
        uu[e] = a.x; uu[e+1] = a.y; uu[e+2] = a.z; uu[e+3] = a.w;
        float4 c = *(const float4*)(Ur + i * 64 + fb + e);
        ur[e] = c.x; ur[e+1] = c.y; ur[e+2] = c.z; ur[e+3] = c.w;
        float4 d = *(const float4*)(Uh + i * 64 + fb + e);
        uh[e] = d.x; uh[e+1] = d.y; uh[e+2] = d.z; uh[e+3] = d.w;
        float4 p = *(const float4*)(Wu + i * 64 + fb + e);
        wu[e] = p.x; wu[e+1] = p.y; wu[e+2] = p.z; wu[e+3] = p.w;
        float4 s = *(const float4*)(Wr + i * 64 + fb + e);
        wr[e] = s.x; wr[e+1] = s.y; wr[e+2] = s.z; wr[e+3] = s.w;
        float4 g = *(const float4*)(Wh + i * 64 + fb + e);
        wh[e] = g.x; wh[e+1] = g.y; wh[e+2] = g.z; wh[e+3] = g.w;
    }
    const float bui = bu[i * 64 + j];
    const float bri = br[i * 64 + j];
    const float bhi = bh[i * 64 + j];
    if (tid < 64) qd[0][tid] = Q0[tid * 64 + j];
    __syncthreads();

    for (int t = 0; t < TT; ++t) {
        float z16[16];
#pragma unroll
        for (int e = 0; e < 16; e += 4) {
            f32x4 z = *(const f32x4*)(&zsh[t][fb + e]);
            z16[e] = z[0]; z16[e+1] = z[1]; z16[e+2] = z[2]; z16[e+3] = z[3];
        }
        float pu = 0.f, pr = 0.f, ph = 0.f;
#pragma unroll
        for (int e = 0; e < 16; ++e) {
            pu += wu[e] * z16[e];
            pr += wr[e] * z16[e];
            ph += wh[e] * z16[e];
        }
        pu += __shfl_xor(pu, 16); pu += __shfl_xor(pu, 32);
        pr += __shfl_xor(pr, 16); pr += __shfl_xor(pr, 32);
        ph += __shfl_xor(ph, 16); ph += __shfl_xor(ph, 32);
        if (fq == 0) {
            wzl[(0 * TT + t) * 64 + i] = pu;
            wzl[(1 * TT + t) * 64 + i] = pr;
            wzl[(2 * TT + t) * 64 + i] = ph;
        }
    }
    __syncthreads();

    int cur = 0;
    for (int t = 0; t < TT; ++t) {
        float q16[16];
#pragma unroll
        for (int e = 0; e < 16; e += 4) {
            f32x4 v = *(const f32x4*)(&qd[cur][fb + e]);
            q16[e] = v[0]; q16[e+1] = v[1]; q16[e+2] = v[2]; q16[e+3] = v[3];
        }
        float su = 0.f, sr = 0.f;
#pragma unroll
        for (int e = 0; e < 16; ++e) { su += uu[e] * q16[e]; sr += ur[e] * q16[e]; }
        su += __shfl_xor(su, 16); su += __shfl_xor(su, 32);
        sr += __shfl_xor(sr, 16); sr += __shfl_xor(sr, 32);
        const float u_ = 1.f / (1.f + expf(-(su + wzl[(0 * TT + t) * 64 + i] + bui)));
        const float r_ = 1.f / (1.f + expf(-(sr + wzl[(1 * TT + t) * 64 + i] + bri)));
        if (fq == 0) rr[i] = r_;
        __syncthreads();                       // B1: rr ready
        float sh = 0.f;
#pragma unroll
        for (int e = 0; e < 16; e += 4) {
            f32x4 v = *(const f32x4*)(&rr[fb + e]);
            sh += uh[e]   * (v[0] * q16[e]);
            sh += uh[e+1] * (v[1] * q16[e+1]);
            sh += uh[e+2] * (v[2] * q16[e+2]);
            sh += uh[e+3] * (v[3] * q16[e+3]);
        }
        sh += __shfl_xor(sh, 16); sh += __shfl_xor(sh, 32);
        float hv = sh + wzl[(2 * TT + t) * 64 + i] + bhi;
        hv = hv > 0.f ? hv : 0.f;
        const float qi = qd[cur][i];
        const float qn = (1.f - u_) * qi + u_ * hv;
        if (fq == 0) {
            qd[cur ^ 1][i] = qn;
            Qtr[(size_t)t * 4096 + j * 64 + i] = f2bf(qn);
        }
        __syncthreads();                       // B2: q[nxt] ready + rr WAR
        cur ^= 1;
    }
}

// ---------------------------------------------------------------------------
// K_C y-MFMA (R17/R22-proven verbatim).
// ---------------------------------------------------------------------------
__global__ __launch_bounds__(256) void ymfma_kernel(
    const unsigned short* __restrict__ Xbf, const unsigned short* __restrict__ Qtr,
    unsigned short* __restrict__ Ytr)
{
    __shared__ __align__(16) unsigned char Qb[8192];   // bf16 [64 j][128B]
    const int t = blockIdx.y, tid = threadIdx.x;
    const int n0 = blockIdx.x * 256;
    const int lane = tid & 63, w = tid >> 6;
    const int lr = lane & 15, lq = lane >> 4;

    const unsigned short* Qp = Qtr + (size_t)t * 4096;
#pragma unroll
    for (int q2 = 0; q2 < 2; ++q2) {
        const int j = (w << 4) + (q2 << 3) + (lane >> 3);
        const unsigned short* g = Qp + (size_t)j * 64 + (((lane & 7) ^ (j & 7)) << 3);
        __builtin_amdgcn_global_load_lds(
            (const __attribute__((address_space(1))) void*)g,
            (__attribute__((address_space(3))) void*)
                (&Qb[((w << 4) + (q2 << 3)) << 7]), 16, 0, 0);
    }
    __syncthreads();

    f32x4 acc[4][4];
#pragma unroll
    for (int jt = 0; jt < 4; ++jt)
#pragma unroll
        for (int nt = 0; nt < 4; ++nt) acc[jt][nt] = (f32x4){0.f, 0.f, 0.f, 0.f};

#pragma unroll
    for (int ks = 0; ks < 2; ++ks) {
        bf16x8 af[4], bf[4];
#pragma unroll
        for (int jt = 0; jt < 4; ++jt) {
            const int j = (jt << 4) + lr;
            const int x = ((ks << 2) + lq) ^ (j & 7);
            af[jt] = *(const bf16x8*)(&Qb[(j << 7) + (x << 4)]);
        }
#pragma unroll
        for (int nt = 0; nt < 4; ++nt) {
            const int n = n0 + (w << 6) + (nt << 4) + lr;
            bf[nt] = __builtin_bit_cast(bf16x8,
                *(const uint4*)(Xbf + ((size_t)t * NN + n) * FF + (ks << 5) + (lq << 3)));
        }
#pragma unroll
        for (int jt = 0; jt < 4; ++jt)
#pragma unroll
            for (int nt = 0; nt < 4; ++nt)
                acc[jt][nt] = __builtin_amdgcn_mfma_f32_16x16x32_bf16(
                    af[jt], bf[nt], acc[jt][nt], 0, 0, 0);
    }

#pragma unroll
    for (int jt = 0; jt < 4; ++jt)
#pragma unroll
        for (int nt = 0; nt < 4; ++nt) {
            const int nn = n0 + (w << 6) + (nt << 4) + lr;
#pragma unroll
            for (int rg = 0; rg < 4; ++rg) {
                const int j = (jt << 4) + (lq << 2) + rg;
                Ytr[(size_t)t * FF * NN + (size_t)j * NN + nn] = f2bf(acc[jt][nt][rg]);
            }
        }
}

// ---------------------------------------------------------------------------
// K_D gemm v2: out[t] = relu(A[t] @ Y[t]).  M=32 tile, 16KB LDS ->
// 8 blocks/CU (32 waves/CU, full occupancy): more desynchronized blocks
// cover each other's barrier-drain holes (R9->R10 mechanism extended).
// Wave (wm,wn) = (w>>1, w&1): rows wm*16, cols wn*32.  Grid 2048,
// XCD-grouped (4 t x 64 mtiles per XCD).  Staging patterns as R10.
// ---------------------------------------------------------------------------
__global__ __launch_bounds__(256, 8) void gemm_kernel(
    const float* __restrict__ A, const unsigned short* __restrict__ Ytr,
    float* __restrict__ out)
{
    __shared__ __align__(16) unsigned char Abuf[8192];   // f32 [32 r][256B]
    __shared__ __align__(16) unsigned char Bbuf[8192];   // bf16 [64 j][128B]
    const int tid = threadIdx.x;
    const int bid = blockIdx.x;
    const int xcd = bid & 7, li = bid >> 3;          // 8 XCDs x 256 blocks
    const int t = (xcd << 2) + (li >> 6);            // 4 timesteps per XCD
    const int m0 = (li & 63) * 32;
    const int lane = tid & 63, w = tid >> 6;
    const int lr = lane & 15, lq = lane >> 4;
    const int wm = w >> 1, wn = w & 1;

    const float* Ap = A + (size_t)t * NN * NN + (size_t)m0 * NN;
    const unsigned short* Yp = Ytr + (size_t)t * FF * NN;

    f32x4 acc[2];
#pragma unroll
    for (int nt = 0; nt < 2; ++nt) acc[nt] = (f32x4){0.f, 0.f, 0.f, 0.f};

    for (int kt = 0; kt < 32; ++kt) {
        const int kk = kt << 6;
        // STAGE A: 32 rows x 256B = 8 instrs; wave w stages rows w*8+q*4+lq
#pragma unroll
        for (int q = 0; q < 2; ++q) {
            const int row = (w << 3) + (q << 2) + lq;
            const float* g = Ap + (size_t)row * NN + kk + ((lr ^ (row & 7)) << 2);
            __builtin_amdgcn_global_load_lds(
                (const __attribute__((address_space(1))) void*)g,
                (__attribute__((address_space(3))) void*)
                    (&Abuf[((w << 3) + (q << 2)) << 8]), 16, 0, 0);
        }
        // STAGE B: identical to R10
#pragma unroll
        for (int q = 0; q < 2; ++q) {
            const int j = (w << 4) + (q << 3) + (lane >> 3);
            const unsigned short* g = Yp + (size_t)j * NN + kk
                                    + (((lane & 7) ^ (j & 7)) << 3);
            __builtin_amdgcn_global_load_lds(
                (const __attribute__((address_space(1))) void*)g,
                (__attribute__((address_space(3))) void*)
                    (&Bbuf[((w << 4) + (q << 3)) << 7]), 16, 0, 0);
        }
        __syncthreads();
        // COMPUTE: wave (wm,wn) -> rows wm*16+lr, cols wn*32 + nt*16
#pragma unroll
        for (int ks = 0; ks < 2; ++ks) {
            const int r = (wm << 4) + lr;
            const int c0 = ((ks << 3) + (lq << 1)) ^ (lr & 7);
            const int c1 = ((ks << 3) + (lq << 1) + 1) ^ (lr & 7);
            const f32x4 a0 = *(const f32x4*)(&Abuf[(r << 8) + (c0 << 4)]);
            const f32x4 a1 = *(const f32x4*)(&Abuf[(r << 8) + (c1 << 4)]);
            bf16x8 af;
            af[0] = (__bf16)a0[0]; af[1] = (__bf16)a0[1];
            af[2] = (__bf16)a0[2]; af[3] = (__bf16)a0[3];
            af[4] = (__bf16)a1[0]; af[5] = (__bf16)a1[1];
            af[6] = (__bf16)a1[2]; af[7] = (__bf16)a1[3];
#pragma unroll
            for (int nt = 0; nt < 2; ++nt) {
                const int j = (wn << 5) + (nt << 4) + lr;
                const int x = ((ks << 2) + lq) ^ (j & 7);
                const bf16x8 bf = *(const bf16x8*)(&Bbuf[(j << 7) + (x << 4)]);
                acc[nt] = __builtin_amdgcn_mfma_f32_16x16x32_bf16(
                    af, bf, acc[nt], 0, 0, 0);
            }
        }
        __syncthreads();
    }

    // store: rows m0 + wm*16 + lq*4 + rg, cols wn*32 + nt*16 + lr
#pragma unroll
    for (int nt = 0; nt < 2; ++nt) {
        const int row0 = m0 + (wm << 4) + (lq << 2);
        const int col = (wn << 5) + (nt << 4) + lr;
#pragma unroll
        for (int rg = 0; rg < 4; ++rg) {
            const float v = acc[nt][rg];
            out[((size_t)t * NN + (row0 + rg)) * FF + col] = v > 0.f ? v : 0.f;
        }
    }
}

// ---------------------------------------------------------------------------
extern "C" void kernel_launch(void* const* d_in, const int* in_sizes, int n_in,
                              void* d_out, int out_size, void* d_ws, size_t ws_size,
                              hipStream_t stream) {
    const float* A      = (const float*)d_in[0];
    const float* X      = (const float*)d_in[1];
    const float* mask   = (const float*)d_in[2];
    const float* Q0     = (const float*)d_in[3];
    const float* scorer = (const float*)d_in[4];
    const float* Wu     = (const float*)d_in[5];
    const float* Uu     = (const float*)d_in[6];
    const float* bu     = (const float*)d_in[7];
    const float* Wr     = (const float*)d_in[8];
    const float* Ur     = (const float*)d_in[9];
    const float* br     = (const float*)d_in[10];
    const float* Wh     = (const float*)d_in[11];
    const float* Uh     = (const float*)d_in[12];
    const float* bh     = (const float*)d_in[13];
    float* out = (float*)d_out;

    float* ws = (float*)d_ws;
    double* scores        = (double*)ws;                          // [32][2048] fp64
    int*    tkidx         = (int*)(ws + 131072);                  // [32][64]
    float*  tkval         = ws + 133120;                          // [32][64]
    unsigned short* Qtr   = (unsigned short*)(ws + 135168);       // [32][64][64] bf16
    unsigned short* Xbf   = (unsigned short*)(ws + 200704);       // [32][2048][64] bf16
    unsigned short* Ytr   = (unsigned short*)(ws + 2297856);      // [32][64][2048] bf16

    score_kernel<<<dim3(8, TT), 256, 0, stream>>>(X, mask, scorer, scores, Xbf);
    select_kernel<<<TT, 1024, 0, stream>>>(scores, tkidx, tkval);
    qchain_kernel<<<FF, 256, 0, stream>>>(Q0, Uu, Ur, Uh, Wu, Wr, Wh,
                                          bu, br, bh, tkidx, tkval, X, Qtr);
    ymfma_kernel<<<dim3(8, TT), 256, 0, stream>>>(Xbf, Qtr, Ytr);
    gemm_kernel<<<2048, 256, 0, stream>>>(A, Ytr, out);
}

// Round 24
// 191.230 us; speedup vs baseline: 1.0233x; 1.0233x over previous
//
#include <hip/hip_runtime.h>
#include <hip/hip_bf16.h>
#include <math.h>

#define TT 32
#define NN 2048
#define FF 64

typedef float f32x4 __attribute__((ext_vector_type(4)));
typedef __bf16 bf16x8 __attribute__((ext_vector_type(8)));
typedef unsigned short u16x8 __attribute__((ext_vector_type(8)));

__device__ __forceinline__ unsigned short f2bf(float f) {
    __bf16 h = (__bf16)f;
    return __builtin_bit_cast(unsigned short, h);
}

// ---------------------------------------------------------------------------
// K_S: wide scoring kernel. grid (8, 32) x 256.  (R22-proven verbatim)
// ---------------------------------------------------------------------------
__global__ __launch_bounds__(256) void score_kernel(
    const float* __restrict__ X, const float* __restrict__ mask,
    const float* __restrict__ scorer,
    double* __restrict__ scores, unsigned short* __restrict__ Xbf)
{
    const int t = blockIdx.y, tid = threadIdx.x;
    const int n = blockIdx.x * 256 + tid;
    __shared__ float scf[64];
    if (tid < 64) scf[tid] = scorer[tid];
    __syncthreads();

    double nrm = 0.0;
#pragma unroll
    for (int f = 0; f < 64; ++f) nrm += (double)scf[f] * (double)scf[f];
    const double inv = 1.0 / sqrt(nrm);

    const float* xr = X + ((size_t)t * NN + n) * FF;
    unsigned short* xo = Xbf + ((size_t)t * NN + n) * FF;
    double s = 0.0;
#pragma unroll
    for (int f = 0; f < 64; f += 4) {
        float4 v = *(const float4*)(xr + f);
        s += (double)v.x * (double)scf[f]   + (double)v.y * (double)scf[f+1]
           + (double)v.z * (double)scf[f+2] + (double)v.w * (double)scf[f+3];
        ushort4 pk = make_ushort4(f2bf(v.x), f2bf(v.y), f2bf(v.z), f2bf(v.w));
        *(ushort4*)(xo + f) = pk;
    }
    scores[t * NN + n] = s * inv + (double)mask[t * NN + n];
}

// ---------------------------------------------------------------------------
// K_A select v4 (R22-proven verbatim): per-wave 128-elem reg bitonic ->
// merge-and-truncate tree -> (idx, tanh(val)).
// ---------------------------------------------------------------------------
__global__ __launch_bounds__(1024) void select_kernel(
    const double* __restrict__ scores,
    int* __restrict__ tkidx, float* __restrict__ tkval)
{
    const int t = blockIdx.x, tid = threadIdx.x;
    const int lane = tid & 63, w = tid >> 6;
    __shared__ double sk[1024];
    __shared__ int    si[1024];

    double v0 = scores[t * NN + (w << 7) + lane];
    double v1 = scores[t * NN + (w << 7) + 64 + lane];
    int    i0 = (w << 7) + lane;
    int    i1 = (w << 7) + 64 + lane;

#define BETTER(av, ai, bv, bi) ((av) > (bv) || ((av) == (bv) && (ai) < (bi)))
#pragma unroll
    for (int k = 2; k <= 128; k <<= 1) {
#pragma unroll
        for (int j = 64; j > 0; j >>= 1) {
            if (j > (k >> 1)) continue;
            if (j == 64) {
                const bool ib = BETTER(v0, i0, v1, i1);
                if (!ib) {
                    const double tv = v0; v0 = v1; v1 = tv;
                    const int ti = i0; i0 = i1; i1 = ti;
                }
            } else {
                {
                    const double pv = __shfl_xor(v0, j);
                    const int    pi = __shfl_xor(i0, j);
                    const bool lower = (lane & j) == 0;
                    const bool up = ((lane & k) == 0);
                    const bool ib = BETTER(v0, i0, pv, pi);
                    const bool keep = (up == lower) ? ib : !ib;
                    if (!keep) { v0 = pv; i0 = pi; }
                }
                {
                    const double pv = __shfl_xor(v1, j);
                    const int    pi = __shfl_xor(i1, j);
                    const bool lower = (lane & j) == 0;
                    const bool up = (k == 64) ? false : ((lane & k) == 0);
                    const bool ib = BETTER(v1, i1, pv, pi);
                    const bool keep = (up == lower) ? ib : !ib;
                    if (!keep) { v1 = pv; i1 = pi; }
                }
            }
        }
    }
    sk[(w << 6) + lane] = v0;
    si[(w << 6) + lane] = i0;
    __syncthreads();

#pragma unroll
    for (int round = 0; round < 4; ++round) {
        const int nl = 8 >> round;
        double cv = 0.0; int ci = 0;
        const bool active = (w < nl);
        if (active) {
            const int la = (w << 1), lb = (w << 1) + 1;
            const double av = sk[(la << 6) + lane];
            const int    ai = si[(la << 6) + lane];
            const double bv = sk[(lb << 6) + 63 - lane];
            const int    bi = si[(lb << 6) + 63 - lane];
            if (BETTER(av, ai, bv, bi)) { cv = av; ci = ai; }
            else                        { cv = bv; ci = bi; }
#pragma unroll
            for (int j = 32; j > 0; j >>= 1) {
                const double pv = __shfl_xor(cv, j);
                const int    pi = __shfl_xor(ci, j);
                const bool lower = (lane & j) == 0;
                const bool ib = BETTER(cv, ci, pv, pi);
                const bool keep = lower ? ib : !ib;
                if (!keep) { cv = pv; ci = pi; }
            }
        }
        __syncthreads();
        if (active) {
            sk[(w << 6) + lane] = cv;
            si[(w << 6) + lane] = ci;
        }
        __syncthreads();
    }
#undef BETTER

    if (tid < 64) {
        tkidx[t * 64 + tid] = si[tid];
        tkval[t * 64 + tid] = tanhf((float)sk[tid]);
    }
}

// ---------------------------------------------------------------------------
// K_B qchain v6 (R20/R22-proven verbatim): 64 blocks x 256, 2 barriers/step.
// ---------------------------------------------------------------------------
__global__ __launch_bounds__(256) void qchain_kernel(
    const float* __restrict__ Q0,
    const float* __restrict__ Uu, const float* __restrict__ Ur,
    const float* __restrict__ Uh,
    const float* __restrict__ Wu, const float* __restrict__ Wr,
    const float* __restrict__ Wh,
    const float* __restrict__ bu, const float* __restrict__ br,
    const float* __restrict__ bh,
    const int* __restrict__ tkidx, const float* __restrict__ tkval,
    const float* __restrict__ X, unsigned short* __restrict__ Qtr)
{
    const int j = blockIdx.x, tid = threadIdx.x;
    const int w = tid >> 6, l = tid & 63;
    const int i = (w << 4) + (l & 15);
    const int fq = l >> 4, fb = fq << 4;

    __shared__ __align__(16) float zsh[TT][64];
    __shared__ __align__(16) float wzl[3 * TT * 64];
    __shared__ __align__(16) float qd[2][64];
    __shared__ __align__(16) float rr[64];

    {
        const int tt = tid >> 3, p8 = (tid & 7) << 3;
        const int idxt = tkidx[tt * 64 + j];
        const float th = tkval[tt * 64 + j];
        const float* xr = X + ((size_t)tt * NN + idxt) * FF + p8;
        float4 v0 = *(const float4*)(xr);
        float4 v1 = *(const float4*)(xr + 4);
        zsh[tt][p8]     = v0.x * th; zsh[tt][p8 + 1] = v0.y * th;
        zsh[tt][p8 + 2] = v0.z * th; zsh[tt][p8 + 3] = v0.w * th;
        zsh[tt][p8 + 4] = v1.x * th; zsh[tt][p8 + 5] = v1.y * th;
        zsh[tt][p8 + 6] = v1.z * th; zsh[tt][p8 + 7] = v1.w * th;
    }

    float uu[16], ur[16], uh[16], wu[16], wr[16], wh[16];
#pragma unroll
    for (int e = 0; e < 16; e += 4) {
        float4 a = *(const float4*)(Uu + i * 64 + fb + e);
        uu[e] = a.x; uu[e+1] = a.y; uu[e+2] = a.z; uu[e+3] = a.w;
        float4 c = *(const float4*)(Ur + i * 64 + fb + e);
        ur[e] = c.x; ur[e+1] = c.y; ur[e+2] = c.z; ur[e+3] = c.w;
        float4 d = *(const float4*)(Uh + i * 64 + fb + e);
        uh[e] = d.x; uh[e+1] = d.y; uh[e+2] = d.z; uh[e+3] = d.w;
        float4 p = *(const float4*)(Wu + i * 64 + fb + e);
        wu[e] = p.x; wu[e+1] = p.y; wu[e+2] = p.z; wu[e+3] = p.w;
        float4 s = *(const float4*)(Wr + i * 64 + fb + e);
        wr[e] = s.x; wr[e+1] = s.y; wr[e+2] = s.z; wr[e+3] = s.w;
        float4 g = *(const float4*)(Wh + i * 64 + fb + e);
        wh[e] = g.x; wh[e+1] = g.y; wh[e+2] = g.z; wh[e+3] = g.w;
    }
    const float bui = bu[i * 64 + j];
    const float bri = br[i * 64 + j];
    const float bhi = bh[i * 64 + j];
    if (tid < 64) qd[0][tid] = Q0[tid * 64 + j];
    __syncthreads();

    for (int t = 0; t < TT; ++t) {
        float z16[16];
#pragma unroll
        for (int e = 0; e < 16; e += 4) {
            f32x4 z = *(const f32x4*)(&zsh[t][fb + e]);
            z16[e] = z[0]; z16[e+1] = z[1]; z16[e+2] = z[2]; z16[e+3] = z[3];
        }
        float pu = 0.f, pr = 0.f, ph = 0.f;
#pragma unroll
        for (int e = 0; e < 16; ++e) {
            pu += wu[e] * z16[e];
            pr += wr[e] * z16[e];
            ph += wh[e] * z16[e];
        }
        pu += __shfl_xor(pu, 16); pu += __shfl_xor(pu, 32);
        pr += __shfl_xor(pr, 16); pr += __shfl_xor(pr, 32);
        ph += __shfl_xor(ph, 16); ph += __shfl_xor(ph, 32);
        if (fq == 0) {
            wzl[(0 * TT + t) * 64 + i] = pu;
            wzl[(1 * TT + t) * 64 + i] = pr;
            wzl[(2 * TT + t) * 64 + i] = ph;
        }
    }
    __syncthreads();

    int cur = 0;
    for (int t = 0; t < TT; ++t) {
        float q16[16];
#pragma unroll
        for (int e = 0; e < 16; e += 4) {
            f32x4 v = *(const f32x4*)(&qd[cur][fb + e]);
            q16[e] = v[0]; q16[e+1] = v[1]; q16[e+2] = v[2]; q16[e+3] = v[3];
        }
        float su = 0.f, sr = 0.f;
#pragma unroll
        for (int e = 0; e < 16; ++e) { su += uu[e] * q16[e]; sr += ur[e] * q16[e]; }
        su += __shfl_xor(su, 16); su += __shfl_xor(su, 32);
        sr += __shfl_xor(sr, 16); sr += __shfl_xor(sr, 32);
        const float u_ = 1.f / (1.f + expf(-(su + wzl[(0 * TT + t) * 64 + i] + bui)));
        const float r_ = 1.f / (1.f + expf(-(sr + wzl[(1 * TT + t) * 64 + i] + bri)));
        if (fq == 0) rr[i] = r_;
        __syncthreads();                       // B1: rr ready
        float sh = 0.f;
#pragma unroll
        for (int e = 0; e < 16; e += 4) {
            f32x4 v = *(const f32x4*)(&rr[fb + e]);
            sh += uh[e]   * (v[0] * q16[e]);
            sh += uh[e+1] * (v[1] * q16[e+1]);
            sh += uh[e+2] * (v[2] * q16[e+2]);
            sh += uh[e+3] * (v[3] * q16[e+3]);
        }
        sh += __shfl_xor(sh, 16); sh += __shfl_xor(sh, 32);
        float hv = sh + wzl[(2 * TT + t) * 64 + i] + bhi;
        hv = hv > 0.f ? hv : 0.f;
        const float qi = qd[cur][i];
        const float qn = (1.f - u_) * qi + u_ * hv;
        if (fq == 0) {
            qd[cur ^ 1][i] = qn;
            Qtr[(size_t)t * 4096 + j * 64 + i] = f2bf(qn);
        }
        __syncthreads();                       // B2: q[nxt] ready + rr WAR
        cur ^= 1;
    }
}

// ---------------------------------------------------------------------------
// K_C y-MFMA (R17/R22-proven verbatim).
// ---------------------------------------------------------------------------
__global__ __launch_bounds__(256) void ymfma_kernel(
    const unsigned short* __restrict__ Xbf, const unsigned short* __restrict__ Qtr,
    unsigned short* __restrict__ Ytr)
{
    __shared__ __align__(16) unsigned char Qb[8192];   // bf16 [64 j][128B]
    const int t = blockIdx.y, tid = threadIdx.x;
    const int n0 = blockIdx.x * 256;
    const int lane = tid & 63, w = tid >> 6;
    const int lr = lane & 15, lq = lane >> 4;

    const unsigned short* Qp = Qtr + (size_t)t * 4096;
#pragma unroll
    for (int q2 = 0; q2 < 2; ++q2) {
        const int j = (w << 4) + (q2 << 3) + (lane >> 3);
        const unsigned short* g = Qp + (size_t)j * 64 + (((lane & 7) ^ (j & 7)) << 3);
        __builtin_amdgcn_global_load_lds(
            (const __attribute__((address_space(1))) void*)g,
            (__attribute__((address_space(3))) void*)
                (&Qb[((w << 4) + (q2 << 3)) << 7]), 16, 0, 0);
    }
    __syncthreads();

    f32x4 acc[4][4];
#pragma unroll
    for (int jt = 0; jt < 4; ++jt)
#pragma unroll
        for (int nt = 0; nt < 4; ++nt) acc[jt][nt] = (f32x4){0.f, 0.f, 0.f, 0.f};

#pragma unroll
    for (int ks = 0; ks < 2; ++ks) {
        bf16x8 af[4], bf[4];
#pragma unroll
        for (int jt = 0; jt < 4; ++jt) {
            const int j = (jt << 4) + lr;
            const int x = ((ks << 2) + lq) ^ (j & 7);
            af[jt] = *(const bf16x8*)(&Qb[(j << 7) + (x << 4)]);
        }
#pragma unroll
        for (int nt = 0; nt < 4; ++nt) {
            const int n = n0 + (w << 6) + (nt << 4) + lr;
            bf[nt] = __builtin_bit_cast(bf16x8,
                *(const uint4*)(Xbf + ((size_t)t * NN + n) * FF + (ks << 5) + (lq << 3)));
        }
#pragma unroll
        for (int jt = 0; jt < 4; ++jt)
#pragma unroll
            for (int nt = 0; nt < 4; ++nt)
                acc[jt][nt] = __builtin_amdgcn_mfma_f32_16x16x32_bf16(
                    af[jt], bf[nt], acc[jt][nt], 0, 0, 0);
    }

#pragma unroll
    for (int jt = 0; jt < 4; ++jt)
#pragma unroll
        for (int nt = 0; nt < 4; ++nt) {
            const int nn = n0 + (w << 6) + (nt << 4) + lr;
#pragma unroll
            for (int rg = 0; rg < 4; ++rg) {
                const int j = (jt << 4) + (lq << 2) + rg;
                Ytr[(size_t)t * FF * NN + (size_t)j * NN + nn] = f2bf(acc[jt][nt][rg]);
            }
        }
}

// ---------------------------------------------------------------------------
// K_D: out[t] = relu(A[t] @ Y[t]).  R10/R22 gemm (measured 112us, 4.6 TB/s):
// M=64 tile, BK=64, 24KB LDS, 4 blocks/CU, 2-barrier loop, chunk-XOR swizzle.
// ---------------------------------------------------------------------------
__global__ __launch_bounds__(256, 4) void gemm_kernel(
    const float* __restrict__ A, const unsigned short* __restrict__ Ytr,
    float* __restrict__ out)
{
    __shared__ __align__(16) unsigned char Abuf[16384];  // f32 [64 r][256B]
    __shared__ __align__(16) unsigned char Bbuf[8192];   // bf16 [64 j][128B]
    const int tid = threadIdx.x;
    const int bid = blockIdx.x;
    const int xcd = bid & 7, li = bid >> 3;          // 8 XCDs x 128 blocks
    const int t = (xcd << 2) + (li >> 5);            // 4 timesteps per XCD
    const int m0 = (li & 31) * 64;
    const int lane = tid & 63, w = tid >> 6;
    const int lr = lane & 15, lq = lane >> 4;

    const float* Ap = A + (size_t)t * NN * NN + (size_t)m0 * NN;
    const unsigned short* Yp = Ytr + (size_t)t * FF * NN;

    f32x4 acc[4];
#pragma unroll
    for (int nt = 0; nt < 4; ++nt) acc[nt] = (f32x4){0.f, 0.f, 0.f, 0.f};

    for (int kt = 0; kt < 32; ++kt) {
        const int kk = kt << 6;
#pragma unroll
        for (int q = 0; q < 4; ++q) {
            const int row = (w << 4) + (q << 2) + lq;
            const float* g = Ap + (size_t)row * NN + kk + ((lr ^ (row & 7)) << 2);
            __builtin_amdgcn_global_load_lds(
                (const __attribute__((address_space(1))) void*)g,
                (__attribute__((address_space(3))) void*)
                    (&Abuf[((w << 4) + (q << 2)) << 8]), 16, 0, 0);
        }
#pragma unroll
        for (int q = 0; q < 2; ++q) {
            const int j = (w << 4) + (q << 3) + (lane >> 3);
            const unsigned short* g = Yp + (size_t)j * NN + kk
                                    + (((lane & 7) ^ (j & 7)) << 3);
            __builtin_amdgcn_global_load_lds(
                (const __attribute__((address_space(1))) void*)g,
                (__attribute__((address_space(3))) void*)
                    (&Bbuf[((w << 4) + (q << 3)) << 7]), 16, 0, 0);
        }
        __syncthreads();
#pragma unroll
        for (int ks = 0; ks < 2; ++ks) {
            const int r = (w << 4) + lr;
            const int c0 = ((ks << 3) + (lq << 1)) ^ (lr & 7);
            const int c1 = ((ks << 3) + (lq << 1) + 1) ^ (lr & 7);
            const f32x4 a0 = *(const f32x4*)(&Abuf[(r << 8) + (c0 << 4)]);
            const f32x4 a1 = *(const f32x4*)(&Abuf[(r << 8) + (c1 << 4)]);
            bf16x8 af;
            af[0] = (__bf16)a0[0]; af[1] = (__bf16)a0[1];
            af[2] = (__bf16)a0[2]; af[3] = (__bf16)a0[3];
            af[4] = (__bf16)a1[0]; af[5] = (__bf16)a1[1];
            af[6] = (__bf16)a1[2]; af[7] = (__bf16)a1[3];
#pragma unroll
            for (int nt = 0; nt < 4; ++nt) {
                const int j = (nt << 4) + lr;
                const int x = ((ks << 2) + lq) ^ (j & 7);
                const bf16x8 bf = *(const bf16x8*)(&Bbuf[(j << 7) + (x << 4)]);
                acc[nt] = __builtin_amdgcn_mfma_f32_16x16x32_bf16(
                    af, bf, acc[nt], 0, 0, 0);
            }
        }
        __syncthreads();
    }

#pragma unroll
    for (int nt = 0; nt < 4; ++nt) {
        const int row0 = m0 + (w << 4) + (lq << 2);
        const int col = (nt << 4) + lr;
#pragma unroll
        for (int rg = 0; rg < 4; ++rg) {
            const float v = acc[nt][rg];
            out[((size_t)t * NN + (row0 + rg)) * FF + col] = v > 0.f ? v : 0.f;
        }
    }
}

// ---------------------------------------------------------------------------
extern "C" void kernel_launch(void* const* d_in, const int* in_sizes, int n_in,
                              void* d_out, int out_size, void* d_ws, size_t ws_size,
                              hipStream_t stream) {
    const float* A      = (const float*)d_in[0];
    const float* X      = (const float*)d_in[1];
    const float* mask   = (const float*)d_in[2];
    const float* Q0     = (const float*)d_in[3];
    const float* scorer = (const float*)d_in[4];
    const float* Wu     = (const float*)d_in[5];
    const float* Uu     = (const float*)d_in[6];
    const float* bu     = (const float*)d_in[7];
    const float* Wr     = (const float*)d_in[8];
    const float* Ur     = (const float*)d_in[9];
    const float* br     = (const float*)d_in[10];
    const float* Wh     = (const float*)d_in[11];
    const float* Uh     = (const float*)d_in[12];
    const float* bh     = (const float*)d_in[13];
    float* out = (float*)d_out;

    float* ws = (float*)d_ws;
    double* scores        = (double*)ws;                          // [32][2048] fp64
    int*    tkidx         = (int*)(ws + 131072);                  // [32][64]
    float*  tkval         = ws + 133120;                          // [32][64]
    unsigned short* Qtr   = (unsigned short*)(ws + 135168);       // [32][64][64] bf16
    unsigned short* Xbf   = (unsigned short*)(ws + 200704);       // [32][2048][64] bf16
    unsigned short* Ytr   = (unsigned short*)(ws + 2297856);      // [32][64][2048] bf16

    score_kernel<<<dim3(8, TT), 256, 0, stream>>>(X, mask, scorer, scores, Xbf);
    select_kernel<<<TT, 1024, 0, stream>>>(scores, tkidx, tkval);
    qchain_kernel<<<FF, 256, 0, stream>>>(Q0, Uu, Ur, Uh, Wu, Wr, Wh,
                                          bu, br, bh, tkidx, tkval, X, Qtr);
    ymfma_kernel<<<dim3(8, TT), 256, 0, stream>>>(Xbf, Qtr, Ytr);
    gemm_kernel<<<1024, 256, 0, stream>>>(A, Ytr, out);
}